// Round 7
// baseline (646.805 us; speedup 1.0000x reference)
//
#include <hip/hip_runtime.h>
#include <hip/hip_bf16.h>
#include <stdint.h>

#define Bb 2
#define Ll 2048
#define Dd 768
#define HID 32
#define BL (Bb*Ll)          // 4096
#define KPAD 32
#define KROWS (KPAD+Ll+16)  // 2096
#define NBLK 512

typedef __hip_bfloat16 bf16;
typedef __attribute__((ext_vector_type(8))) short short8;
typedef __attribute__((ext_vector_type(4))) short short4s;
typedef __attribute__((ext_vector_type(4))) float floatx4;

__device__ __forceinline__ float b2f(short u) {
    union { float f; unsigned i; } x; x.i = ((unsigned)(unsigned short)u) << 16; return x.f;
}
__device__ __forceinline__ bf16 f2b(float x) { return __float2bfloat16(x); }
__device__ __forceinline__ short f2bs(float x) {
    bf16 t = __float2bfloat16(x);
    union { bf16 h; short s; } u; u.h = t; return u.s;
}

typedef __attribute__((address_space(1))) const unsigned int guint;
typedef __attribute__((address_space(3))) unsigned int luint;
__device__ __forceinline__ void gload16(const bf16* g, bf16* l) {
    __builtin_amdgcn_global_load_lds((guint*)g, (luint*)l, 16, 0, 0);
}

struct KParams {
    const float *hidden, *sal, *gw1, *gb1, *gw2, *gb2;
    const float *wq, *bq, *wk, *bk, *wv, *bv, *wo, *bo;
    bf16 *h_b, *q_b, *kpd, *vT, *m_b, *w_b;
    float *g2T, *out;
    unsigned *sync;          // [0]=cnt, [1]=gen (memset to 0 per call)
};

#define CONV_VB 2304                 // 4*768*768/4 float4 / 256
#define KP_VB   (Bb*48)              // 96
#define VT_VB   ((Bb*Dd*48)/256)     // 288
#define TR_VB   96
#define PREP_VB (CONV_VB+KP_VB+VT_VB+TR_VB)   // 2784

union SM {
    struct { bf16 As[128 * 64]; bf16 Bs[128 * 64]; } g;   // 32 KB (gemm stages)
    float h1s[8][HID];                                    // gate stage
    bf16 wlds[4][16 * 64];                                // attn stage
};

// manual grid barrier: device-scope atomics; __threadfence emits the L2
// writeback/invalidate needed for cross-XCD visibility (Guideline 16).
__device__ __forceinline__ void gsync(unsigned* cnt, unsigned* gen) {
    __syncthreads();
    if (threadIdx.x == 0) {
        __threadfence();   // release: make this block's writes device-visible
        unsigned g = __hip_atomic_load(gen, __ATOMIC_RELAXED, __HIP_MEMORY_SCOPE_AGENT);
        unsigned a = __hip_atomic_fetch_add(cnt, 1u, __ATOMIC_ACQ_REL, __HIP_MEMORY_SCOPE_AGENT);
        if (a == NBLK - 1u) {
            __hip_atomic_store(cnt, 0u, __ATOMIC_RELAXED, __HIP_MEMORY_SCOPE_AGENT);
            __hip_atomic_store(gen, g + 1u, __ATOMIC_RELEASE, __HIP_MEMORY_SCOPE_AGENT);
        } else {
            while (__hip_atomic_load(gen, __ATOMIC_ACQUIRE, __HIP_MEMORY_SCOPE_AGENT) == g)
                __builtin_amdgcn_s_sleep(2);
        }
        __threadfence();   // acquire: invalidate stale cached lines
    }
    __syncthreads();
}

// ---------------- m97-structure MFMA GEMM core (validated, round 5) ----------------
template<int NF>
__device__ __forceinline__ void gemm_core(const bf16* __restrict__ Ag, const bf16* __restrict__ Wg,
                                          int m0, int n0, bf16* As, bf16* Bs,
                                          floatx4 (&acc)[4][NF]) {
    const int tid  = threadIdx.x;
    const int wave = tid >> 6, lane = tid & 63;
    const int lrow = lane & 15, koff = (lane >> 4) * 8;
    const int wm = (wave >> 1) * 64, wn = (wave & 1) * (NF * 16);
    const char* Asb = (const char*)As;
    const char* Bsb = (const char*)Bs;

    for (int k0 = 0; k0 < Dd; k0 += 64) {
#pragma unroll
        for (int c = 0; c < 4; ++c) {
            int p = tid * 16 + c * 4096;
            int r = p >> 7;
            int o = (p & 127) ^ ((r & 7) << 4);
            gload16(Ag + (size_t)(m0 + r) * Dd + k0 + (o >> 1),
                    As + (wave * 1024 + c * 4096) / 2);
        }
#pragma unroll
        for (int c = 0; c < NF; ++c) {
            int p = tid * 16 + c * 4096;
            int r = p >> 7;
            int o = (p & 127) ^ ((r & 7) << 4);
            gload16(Wg + (size_t)(n0 + r) * Dd + k0 + (o >> 1),
                    Bs + (wave * 1024 + c * 4096) / 2);
        }
        __syncthreads();
#pragma unroll
        for (int kk = 0; kk < 64; kk += 32) {
            short8 a[4], b[NF];
#pragma unroll
            for (int i = 0; i < 4; ++i) {
                int row = wm + i * 16 + lrow;
                int byt = (row << 7) + (((kk + koff) * 2) ^ ((row & 7) << 4));
                a[i] = *reinterpret_cast<const short8*>(Asb + byt);
            }
#pragma unroll
            for (int j = 0; j < NF; ++j) {
                int row = wn + j * 16 + lrow;
                int byt = (row << 7) + (((kk + koff) * 2) ^ ((row & 7) << 4));
                b[j] = *reinterpret_cast<const short8*>(Bsb + byt);
            }
#pragma unroll
            for (int i = 0; i < 4; ++i)
#pragma unroll
                for (int j = 0; j < NF; ++j)
                    acc[i][j] = __builtin_amdgcn_mfma_f32_16x16x32_bf16(a[i], b[j], acc[i][j], 0, 0, 0);
        }
        __syncthreads();
    }
}

__global__ __launch_bounds__(256, 2) void fused_kernel(KParams P) {
    __shared__ SM smem;
    const int bid = blockIdx.x;           // 512
    const int tid = threadIdx.x;          // 256

    // ============ stage 1: prep (weights->bf16, K/V pads, gw2 transpose) ============
    for (int vb = bid; vb < PREP_VB; vb += NBLK) {
        if (vb < CONV_VB) {
            int idx = vb * 256 + tid;
            const int per = Dd * Dd / 4;
            int w = idx / per, r = idx % per;
            const float* src = (w == 0) ? P.wq : (w == 1) ? P.wk : (w == 2) ? P.wv : P.wo;
            float4 v = reinterpret_cast<const float4*>(src)[r];
            bf16* o = P.w_b + (size_t)w * Dd * Dd + (size_t)r * 4;
            o[0] = f2b(v.x); o[1] = f2b(v.y); o[2] = f2b(v.z); o[3] = f2b(v.w);
        } else if (vb < CONV_VB + KP_VB) {
            int pb = vb - CONV_VB;
            int b = pb / 48, c = pb % 48;
            int row = (c < 32) ? c : (KPAD + Ll + (c - 32));
            size_t base = ((size_t)b * KROWS + row) * Dd;
            for (int i = tid; i < Dd; i += 256)
                P.kpd[base + i] = (c < 32) ? f2b(P.bk[i]) : f2b(0.f);
        } else if (vb < CONV_VB + KP_VB + VT_VB) {
            int o = (vb - CONV_VB - KP_VB) * 256 + tid;
            int b = o / (Dd * 48); int rem = o - b * Dd * 48;
            int n = rem / 48, c = rem % 48;
            int col = (c < 32) ? c : (KPAD + Ll + (c - 32));
            P.vT[((size_t)b * Dd + n) * KROWS + col] = (c < 32) ? f2b(P.bv[n]) : f2b(0.f);
        } else {
            int o = (vb - CONV_VB - KP_VB - VT_VB) * 256 + tid;
            int j = o / Dd, d = o - j * Dd;
            P.g2T[o] = P.gw2[d * HID + j];
        }
    }
    gsync(P.sync, P.sync + 1);

    // ============ stage 2: gate MLP + h = hidden*gate (8 rows/block) ============
    {
        int row0 = bid * 8;
        {
            int rr = tid >> 5, j = tid & 31;
            float s = P.sal[row0 + rr];
            float x = s * P.gw1[j] + P.gb1[j];
            smem.h1s[rr][j] = x / (1.f + __expf(-x));   // silu
        }
        __syncthreads();
#pragma unroll
        for (int dl = 0; dl < 3; ++dl) {
            int d = tid + dl * 256;
            float base = P.gb2[d];
            float acc[8];
#pragma unroll
            for (int rr = 0; rr < 8; ++rr) acc[rr] = base;
#pragma unroll
            for (int j = 0; j < HID; ++j) {
                float wj = P.g2T[j * Dd + d];
#pragma unroll
                for (int rr = 0; rr < 8; ++rr) acc[rr] += smem.h1s[rr][j] * wj;
            }
#pragma unroll
            for (int rr = 0; rr < 8; ++rr) {
                float g = 1.f / (1.f + __expf(-acc[rr]));
                g = fminf(fmaxf(g, 0.05f), 0.95f);
                size_t off = (size_t)(row0 + rr) * Dd + d;
                P.h_b[off] = f2b(P.hidden[off] * g);
            }
        }
    }
    gsync(P.sync, P.sync + 1);

    // ============ stage 3: QKV GEMM, 576 tiles of 128x128 (strided) ============
    for (int t = bid; t < 576; t += NBLK) {
        int xcd = t & 7, idx = t >> 3;
        int mtile = (xcd >> 1) * 8 + (idx & 7);
        int ntile = (xcd & 1) * 9 + (idx >> 3);
        int tgt = ntile / 6;
        int n0 = (ntile % 6) * 128;
        int m0 = mtile * 128;
        const bf16* W = P.w_b + (size_t)tgt * Dd * Dd;
        const float* bias = (tgt == 0) ? P.bq : (tgt == 1) ? P.bk : P.bv;

        floatx4 acc[4][4] = {};
        gemm_core<4>(P.h_b, W, m0, n0, smem.g.As, smem.g.Bs, acc);

        int wave = tid >> 6, lane = tid & 63;
        int wm = (wave >> 1) * 64, wn = (wave & 1) * 64;
        int crow = (lane >> 4) * 4, ccol = lane & 15;
#pragma unroll
        for (int i = 0; i < 4; ++i)
#pragma unroll
            for (int j = 0; j < 4; ++j) {
                int n = n0 + wn + j * 16 + ccol;
                float bb = bias[n];
                int m = m0 + wm + i * 16 + crow;
                int b_ = m >> 11, l = m & 2047;
                if (tgt == 2) {
                    short4s pk;
#pragma unroll
                    for (int rr = 0; rr < 4; ++rr) pk[rr] = f2bs(acc[i][j][rr] + bb);
                    *reinterpret_cast<short4s*>(P.vT + ((size_t)b_ * Dd + n) * KROWS + KPAD + l) = pk;
                } else {
#pragma unroll
                    for (int rr = 0; rr < 4; ++rr) {
                        size_t orow = (tgt == 0) ? (size_t)(m + rr)
                                                 : ((size_t)b_ * KROWS + KPAD + l + rr);
                        bf16* outp = (tgt == 0) ? P.q_b : P.kpd;
                        outp[orow * Dd + n] = f2b(acc[i][j][rr] + bb);
                    }
                }
            }
    }
    gsync(P.sync, P.sync + 1);

    // ============ stage 4: banded MFMA attention, 2048 wave-tasks ============
    {
        const int wv = tid >> 6, lane = tid & 63;
        int w = bid * 4 + wv;                      // 0..2047
        int g = w >> 3, ns = w & 7;
        int b = g >> 7, L0 = (g & 127) * 16;
        const int lrow = lane & 15, koff = (lane >> 4) * 8;
        const int crow = (lane >> 4) * 4, ccol = lane & 15;
        const float scale = 0.03608439182435161f;  // 1/sqrt(768)
        bf16* wlds = smem.wlds[wv];

        const bf16* qbase = P.q_b + ((size_t)(b * Ll + L0 + lrow)) * Dd + koff;
        const bf16* kbase = P.kpd + ((size_t)b * KROWS + L0 + lrow) * Dd + koff;
        floatx4 s[4] = {};
        for (int ks = 0; ks < 24; ++ks) {
            short8 a = *reinterpret_cast<const short8*>(qbase + ks * 32);
#pragma unroll
            for (int f = 0; f < 4; ++f) {
                short8 bb = *reinterpret_cast<const short8*>(kbase + (size_t)f * 16 * Dd + ks * 32);
                s[f] = __builtin_amdgcn_mfma_f32_16x16x32_bf16(a, bb, s[f], 0, 0, 0);
            }
        }
#pragma unroll
        for (int rr = 0; rr < 4; ++rr) {
            int r = crow + rr;
            float z[4], e[4];
#pragma unroll
            for (int f = 0; f < 4; ++f) {
                int j = f * 16 + ccol;
                bool valid = (j >= r + 1) && (j <= r + 32);
                z[f] = valid ? s[f][rr] * scale : -3.0e38f;
            }
            float m = fmaxf(fmaxf(z[0], z[1]), fmaxf(z[2], z[3]));
#pragma unroll
            for (int off = 1; off < 16; off <<= 1) m = fmaxf(m, __shfl_xor(m, off));
            float S32 = 0.f, S8 = 0.f;
#pragma unroll
            for (int f = 0; f < 4; ++f) {
                e[f] = __expf(z[f] - m);
                S32 += e[f];
                int j = f * 16 + ccol;
                S8 += ((j >= r + 25) && (j <= r + 32)) ? e[f] : 0.f;
            }
#pragma unroll
            for (int off = 1; off < 16; off <<= 1) {
                S32 += __shfl_xor(S32, off);
                S8  += __shfl_xor(S8, off);
            }
            float i32 = 0.5f / S32, i8 = 0.5f / S8;
#pragma unroll
            for (int f = 0; f < 4; ++f) {
                int j = f * 16 + ccol;
                float wgt = e[f] * i32 + (((j >= r + 25) && (j <= r + 32)) ? e[f] * i8 : 0.f);
                int byt = ((r * 64 + j) * 2) ^ ((r & 7) << 4);
                *reinterpret_cast<bf16*>(reinterpret_cast<char*>(wlds) + byt) = f2b(wgt);
            }
        }
        __syncthreads();

        short8 wa[2];
#pragma unroll
        for (int ks = 0; ks < 2; ++ks) {
            int byt = ((lrow * 64 + ks * 32 + koff) * 2) ^ ((lrow & 7) << 4);
            wa[ks] = *reinterpret_cast<const short8*>(reinterpret_cast<const char*>(wlds) + byt);
        }
        const bf16* vbase = P.vT + (size_t)b * Dd * KROWS + L0;
        bf16* obase = P.m_b + ((size_t)(b * Ll + L0 + ccol)) * Dd;
#pragma unroll
        for (int fn = 0; fn < 6; ++fn) {
            int nr = ns * 96 + fn * 16;
            floatx4 acc = {};
#pragma unroll
            for (int ks = 0; ks < 2; ++ks) {
                short8 bb = *reinterpret_cast<const short8*>(vbase + (size_t)(nr + lrow) * KROWS + ks * 32 + koff);
                acc = __builtin_amdgcn_mfma_f32_16x16x32_bf16(bb, wa[ks], acc, 0, 0, 0);
            }
            short4s pk;
#pragma unroll
            for (int rr = 0; rr < 4; ++rr) pk[rr] = f2bs(acc[rr]);
            *reinterpret_cast<short4s*>(obase + nr + crow) = pk;
        }
    }
    gsync(P.sync, P.sync + 1);

    // ============ stage 5: output GEMM, 384 tiles of 128x64 ============
    if (bid < 384) {
        int xcd = bid & 7, idx = bid >> 3;
        int mtile = (xcd >> 1) * 8 + (idx & 7);
        int ntile = (xcd & 1) * 6 + (idx >> 3);
        int n0 = ntile * 64, m0 = mtile * 128;
        const bf16* Wg = P.w_b + (size_t)3 * Dd * Dd;

        floatx4 acc[4][2] = {};
        gemm_core<2>(P.m_b, Wg, m0, n0, smem.g.As, smem.g.Bs, acc);

        int wave = tid >> 6, lane = tid & 63;
        int wm = (wave >> 1) * 64, wn = (wave & 1) * 32;
        int crow = (lane >> 4) * 4, ccol = lane & 15;
#pragma unroll
        for (int i = 0; i < 4; ++i)
#pragma unroll
            for (int j = 0; j < 2; ++j) {
                int n = n0 + wn + j * 16 + ccol;
                float bb = P.bo[n];
#pragma unroll
                for (int rr = 0; rr < 4; ++rr) {
                    int m = m0 + wm + i * 16 + crow + rr;
                    size_t o = (size_t)m * Dd + n;
                    P.out[o] = acc[i][j][rr] + bb + b2f(*(const short*)(P.h_b + o));
                }
            }
    }
}

extern "C" void kernel_launch(void* const* d_in, const int* in_sizes, int n_in,
                              void* d_out, int out_size, void* d_ws, size_t ws_size,
                              hipStream_t stream) {
    const size_t nBL  = (size_t)BL * Dd;
    const size_t nPad = (size_t)Bb * KROWS * Dd;
    char* p = (char*)d_ws;
    unsigned* syncc = (unsigned*)p; p += 256;
    bf16* h_b = (bf16*)p; p += nBL * 2;
    bf16* q_b = (bf16*)p; p += nBL * 2;
    bf16* kpd = (bf16*)p; p += nPad * 2;
    bf16* vT  = (bf16*)p; p += nPad * 2;
    bf16* m_b = (bf16*)p; p += nBL * 2;
    bf16* w_b = (bf16*)p; p += (size_t)4 * Dd * Dd * 2;
    float* g2T = (float*)p; p += (size_t)HID * Dd * 4;

    KParams P;
    P.hidden = (const float*)d_in[0];
    P.sal    = (const float*)d_in[1];
    P.gw1    = (const float*)d_in[2];
    P.gb1    = (const float*)d_in[3];
    P.gw2    = (const float*)d_in[4];
    P.gb2    = (const float*)d_in[5];
    P.wq     = (const float*)d_in[6];
    P.bq     = (const float*)d_in[7];
    P.wk     = (const float*)d_in[8];
    P.bk     = (const float*)d_in[9];
    P.wv     = (const float*)d_in[10];
    P.bv     = (const float*)d_in[11];
    P.wo     = (const float*)d_in[12];
    P.bo     = (const float*)d_in[13];
    P.h_b = h_b; P.q_b = q_b; P.kpd = kpd; P.vT = vT; P.m_b = m_b; P.w_b = w_b;
    P.g2T = g2T; P.out = (float*)d_out;
    P.sync = syncc;

    hipMemsetAsync(syncc, 0, 256, stream);
    fused_kernel<<<dim3(NBLK), dim3(256), 0, stream>>>(P);
}

// Round 8
// 79.678 us; speedup vs baseline: 8.1177x; 8.1177x over previous
//
#include <hip/hip_runtime.h>
#include <hip/hip_bf16.h>
#include <stdint.h>

#define Bb 2
#define Ll 2048
#define Dd 768
#define HID 32
#define BL (Bb*Ll)          // 4096
#define KPAD 32
#define KROWS (KPAD+Ll+16)  // 2096

typedef __hip_bfloat16 bf16;
typedef __attribute__((ext_vector_type(8))) short short8;
typedef __attribute__((ext_vector_type(4))) short short4s;
typedef __attribute__((ext_vector_type(4))) float floatx4;

__device__ __forceinline__ float b2f(short u) {
    union { float f; unsigned i; } x; x.i = ((unsigned)(unsigned short)u) << 16; return x.f;
}
__device__ __forceinline__ bf16 f2b(float x) { return __float2bfloat16(x); }
__device__ __forceinline__ short f2bs(float x) {
    bf16 t = __float2bfloat16(x);
    union { bf16 h; short s; } u; u.h = t; return u.s;
}

typedef __attribute__((address_space(1))) const unsigned int guint;
typedef __attribute__((address_space(3))) unsigned int luint;
__device__ __forceinline__ void gload16(const bf16* g, bf16* l) {
    __builtin_amdgcn_global_load_lds((guint*)g, (luint*)l, 16, 0, 0);
}

// ============ prep (weights->bf16, K/V pads) + gate MLP, fused, independent blocks ============
#define CONV_VB 2304                 // 4*768*768/4 float4 / 256
#define KP_VB   (Bb*48)              // 96
#define VT_VB   ((Bb*Dd*48)/256)     // 288
#define PREP_VB (CONV_VB+KP_VB+VT_VB)   // 2688
#define GATE_VB (BL/8)               // 512
__global__ __launch_bounds__(256) void prep_gate_kernel(
        const float* __restrict__ wq, const float* __restrict__ wk,
        const float* __restrict__ wv, const float* __restrict__ wo,
        const float* __restrict__ bk, const float* __restrict__ bv,
        const float* __restrict__ hidden, const float* __restrict__ sal,
        const float* __restrict__ gw1, const float* __restrict__ gb1,
        const float* __restrict__ gw2, const float* __restrict__ gb2,
        bf16* __restrict__ wout, bf16* __restrict__ kp, bf16* __restrict__ vT,
        bf16* __restrict__ h_b) {
    __shared__ bf16 g2t[32 * 770];      // transposed gw2, row-padded to 770 (bank-clean)
    __shared__ float h1s[8][HID];
    int bx = blockIdx.x, tid = threadIdx.x;
    if (bx < CONV_VB) {
        int idx = bx * 256 + tid;
        const int per = Dd * Dd / 4;
        int w = idx / per, r = idx % per;
        const float* src = (w == 0) ? wq : (w == 1) ? wk : (w == 2) ? wv : wo;
        float4 v = reinterpret_cast<const float4*>(src)[r];
        bf16* o = wout + (size_t)w * Dd * Dd + (size_t)r * 4;
        o[0] = f2b(v.x); o[1] = f2b(v.y); o[2] = f2b(v.z); o[3] = f2b(v.w);
    } else if (bx < CONV_VB + KP_VB) {
        int pb = bx - CONV_VB;
        int b = pb / 48, c = pb % 48;
        int row = (c < 32) ? c : (KPAD + Ll + (c - 32));
        size_t base = ((size_t)b * KROWS + row) * Dd;
        for (int i = tid; i < Dd; i += 256)
            kp[base + i] = (c < 32) ? f2b(bk[i]) : f2b(0.f);
    } else if (bx < PREP_VB) {
        int o = (bx - CONV_VB - KP_VB) * 256 + tid;
        int b = o / (Dd * 48); int rem = o - b * Dd * 48;
        int n = rem / 48, c = rem % 48;
        int col = (c < 32) ? c : (KPAD + Ll + (c - 32));
        vT[((size_t)b * Dd + n) * KROWS + col] = (c < 32) ? f2b(bv[n]) : f2b(0.f);
    } else {
        // ---- gate: 8 rows per block; per-block gw2 transpose into LDS (bf16) ----
        int row0 = (bx - PREP_VB) * 8;
#pragma unroll
        for (int k2 = 0; k2 < 24; ++k2) {              // 768*32 fp32 via float4
            int o4 = tid + k2 * 256;
            float4 v = reinterpret_cast<const float4*>(gw2)[o4];
            int d = o4 >> 3, j = (o4 & 7) * 4;         // flat = d*32 + j
            g2t[(j + 0) * 770 + d] = f2b(v.x);
            g2t[(j + 1) * 770 + d] = f2b(v.y);
            g2t[(j + 2) * 770 + d] = f2b(v.z);
            g2t[(j + 3) * 770 + d] = f2b(v.w);
        }
        {
            int rr = tid >> 5, j = tid & 31;
            float s = sal[row0 + rr];
            float x = s * gw1[j] + gb1[j];
            h1s[rr][j] = x / (1.f + __expf(-x));       // silu
        }
        __syncthreads();
#pragma unroll
        for (int dl = 0; dl < 3; ++dl) {
            int d = tid + dl * 256;
            float base = gb2[d];
            float acc[8];
#pragma unroll
            for (int rr = 0; rr < 8; ++rr) acc[rr] = base;
#pragma unroll
            for (int j = 0; j < HID; ++j) {
                float wj = b2f(*(const short*)&g2t[j * 770 + d]);   // 2-way alias = free
#pragma unroll
                for (int rr = 0; rr < 8; ++rr) acc[rr] += h1s[rr][j] * wj;
            }
#pragma unroll
            for (int rr = 0; rr < 8; ++rr) {
                float g = 1.f / (1.f + __expf(-acc[rr]));
                g = fminf(fmaxf(g, 0.05f), 0.95f);
                size_t off = (size_t)(row0 + rr) * Dd + d;
                h_b[off] = f2b(hidden[off] * g);
            }
        }
    }
}

// ---------------- m97-structure MFMA GEMM core, BK-parametric ----------------
template<int NF, int BK>   // NF: wave n-frags (4 -> BN=128, 2 -> BN=64); BK: 64 or 128
__device__ __forceinline__ void gemm_core(const bf16* __restrict__ Ag, const bf16* __restrict__ Wg,
                                          int m0, int n0, bf16* As, bf16* Bs,
                                          floatx4 (&acc)[4][NF]) {
    const int tid  = threadIdx.x;
    const int wave = tid >> 6, lane = tid & 63;
    const int lrow = lane & 15, koff = (lane >> 4) * 8;
    const int wm = (wave >> 1) * 64, wn = (wave & 1) * (NF * 16);
    const int RS = BK * 2;                 // LDS row stride in bytes
    const char* Asb = (const char*)As;
    const char* Bsb = (const char*)Bs;

    for (int k0 = 0; k0 < Dd; k0 += BK) {
#pragma unroll
        for (int c = 0; c < BK / 16; ++c) {        // A: 128 x BK
            int p = tid * 16 + c * 4096;
            int r = p / RS;
            int o = (p % RS) ^ ((r & 7) << 4);
            gload16(Ag + (size_t)(m0 + r) * Dd + k0 + (o >> 1),
                    As + (wave * 1024 + c * 4096) / 2);
        }
#pragma unroll
        for (int c = 0; c < NF * BK / 64; ++c) {   // B: NF*32 x BK
            int p = tid * 16 + c * 4096;
            int r = p / RS;
            int o = (p % RS) ^ ((r & 7) << 4);
            gload16(Wg + (size_t)(n0 + r) * Dd + k0 + (o >> 1),
                    Bs + (wave * 1024 + c * 4096) / 2);
        }
        __syncthreads();
#pragma unroll
        for (int kk = 0; kk < BK; kk += 32) {
            short8 a[4], b[NF];
#pragma unroll
            for (int i = 0; i < 4; ++i) {
                int row = wm + i * 16 + lrow;
                int byt = row * RS + (((kk + koff) * 2) ^ ((row & 7) << 4));
                a[i] = *reinterpret_cast<const short8*>(Asb + byt);
            }
#pragma unroll
            for (int j = 0; j < NF; ++j) {
                int row = wn + j * 16 + lrow;
                int byt = row * RS + (((kk + koff) * 2) ^ ((row & 7) << 4));
                b[j] = *reinterpret_cast<const short8*>(Bsb + byt);
            }
#pragma unroll
            for (int i = 0; i < 4; ++i)
#pragma unroll
                for (int j = 0; j < NF; ++j)
                    acc[i][j] = __builtin_amdgcn_mfma_f32_16x16x32_bf16(a[i], b[j], acc[i][j], 0, 0, 0);
        }
        __syncthreads();
    }
}

// ---------------- fused QKV GEMM (BK=128), k/v into padded arrays ----------------
__global__ __launch_bounds__(256, 2) void gemm_qkv(
        const bf16* __restrict__ A, const bf16* __restrict__ W3,
        const float* __restrict__ bq, const float* __restrict__ bk, const float* __restrict__ bv,
        bf16* __restrict__ qo, bf16* __restrict__ kp, bf16* __restrict__ vT) {
    __shared__ bf16 As[128 * 128];
    __shared__ bf16 Bs[128 * 128];
    int bid = blockIdx.x;
    int xcd = bid & 7, idx = bid >> 3;
    int mtile = (xcd >> 1) * 8 + (idx & 7);
    int ntile = (xcd & 1) * 9 + (idx >> 3);
    int tgt = ntile / 6;
    int n0 = (ntile % 6) * 128;
    int m0 = mtile * 128;
    const bf16* W = W3 + (size_t)tgt * Dd * Dd;
    const float* bias = (tgt == 0) ? bq : (tgt == 1) ? bk : bv;

    floatx4 acc[4][4] = {};
    gemm_core<4, 128>(A, W, m0, n0, As, Bs, acc);

    int wave = threadIdx.x >> 6, lane = threadIdx.x & 63;
    int wm = (wave >> 1) * 64, wn = (wave & 1) * 64;
    int crow = (lane >> 4) * 4, ccol = lane & 15;
#pragma unroll
    for (int i = 0; i < 4; ++i)
#pragma unroll
        for (int j = 0; j < 4; ++j) {
            int n = n0 + wn + j * 16 + ccol;
            float bb = bias[n];
            int m = m0 + wm + i * 16 + crow;
            int b_ = m >> 11, l = m & 2047;
            if (tgt == 2) {
                short4s pk;
#pragma unroll
                for (int rr = 0; rr < 4; ++rr) pk[rr] = f2bs(acc[i][j][rr] + bb);
                *reinterpret_cast<short4s*>(vT + ((size_t)b_ * Dd + n) * KROWS + KPAD + l) = pk;
            } else {
#pragma unroll
                for (int rr = 0; rr < 4; ++rr) {
                    size_t orow = (tgt == 0) ? (size_t)(m + rr)
                                             : ((size_t)b_ * KROWS + KPAD + l + rr);
                    bf16* outp = (tgt == 0) ? qo : kp;
                    outp[orow * Dd + n] = f2b(acc[i][j][rr] + bb);
                }
            }
        }
}

// ---------------- output GEMM (BK=64): out = merged @ wo^T + bo + h ----------------
__global__ __launch_bounds__(256, 2) void gemm_out(
        const bf16* __restrict__ A, const bf16* __restrict__ W,
        const float* __restrict__ bias, const bf16* __restrict__ addend,
        float* __restrict__ out) {
    __shared__ bf16 As[128 * 64];
    __shared__ bf16 Bs[64 * 64];
    int bid = blockIdx.x;
    int xcd = bid & 7, idx = bid >> 3;
    int mtile = (xcd >> 1) * 8 + (idx & 7);
    int ntile = (xcd & 1) * 6 + (idx >> 3);
    int n0 = ntile * 64, m0 = mtile * 128;

    floatx4 acc[4][2] = {};
    gemm_core<2, 64>(A, W, m0, n0, As, Bs, acc);

    int wave = threadIdx.x >> 6, lane = threadIdx.x & 63;
    int wm = (wave >> 1) * 64, wn = (wave & 1) * 32;
    int crow = (lane >> 4) * 4, ccol = lane & 15;
#pragma unroll
    for (int i = 0; i < 4; ++i)
#pragma unroll
        for (int j = 0; j < 2; ++j) {
            int n = n0 + wn + j * 16 + ccol;
            float bb = bias[n];
#pragma unroll
            for (int rr = 0; rr < 4; ++rr) {
                int m = m0 + wm + i * 16 + crow + rr;
                size_t o = (size_t)m * Dd + n;
                out[o] = acc[i][j][rr] + bb + b2f(*(const short*)(addend + o));
            }
        }
}

// ---------------- MFMA banded sliding-window attention (validated round 5) ----------------
__global__ __launch_bounds__(64) void attn_kernel(
        const bf16* __restrict__ q, const bf16* __restrict__ kp, const bf16* __restrict__ vT,
        bf16* __restrict__ merged) {
    __shared__ bf16 wlds[16 * 64];
    const int lane = threadIdx.x;
    const int bid = blockIdx.x;                    // 256
    const int g = (bid & 7) * 32 + (bid >> 3);     // XCD-chunked, bijective
    const int b = g >> 7, L0 = (g & 127) * 16;
    const int lrow = lane & 15, koff = (lane >> 4) * 8;
    const int crow = (lane >> 4) * 4, ccol = lane & 15;
    const float scale = 0.03608439182435161f;      // 1/sqrt(768)

    const bf16* qbase = q  + ((size_t)(b * Ll + L0 + lrow)) * Dd + koff;
    const bf16* kbase = kp + ((size_t)b * KROWS + L0 + lrow) * Dd + koff;
    floatx4 s[4] = {};
    for (int ks = 0; ks < 24; ++ks) {
        short8 a = *reinterpret_cast<const short8*>(qbase + ks * 32);
#pragma unroll
        for (int f = 0; f < 4; ++f) {
            short8 bb = *reinterpret_cast<const short8*>(kbase + (size_t)f * 16 * Dd + ks * 32);
            s[f] = __builtin_amdgcn_mfma_f32_16x16x32_bf16(a, bb, s[f], 0, 0, 0);
        }
    }
#pragma unroll
    for (int rr = 0; rr < 4; ++rr) {
        int r = crow + rr;
        float z[4], e[4];
#pragma unroll
        for (int f = 0; f < 4; ++f) {
            int j = f * 16 + ccol;
            bool valid = (j >= r + 1) && (j <= r + 32);
            z[f] = valid ? s[f][rr] * scale : -3.0e38f;
        }
        float m = fmaxf(fmaxf(z[0], z[1]), fmaxf(z[2], z[3]));
#pragma unroll
        for (int off = 1; off < 16; off <<= 1) m = fmaxf(m, __shfl_xor(m, off));
        float S32 = 0.f, S8 = 0.f;
#pragma unroll
        for (int f = 0; f < 4; ++f) {
            e[f] = __expf(z[f] - m);
            S32 += e[f];
            int j = f * 16 + ccol;
            S8 += ((j >= r + 25) && (j <= r + 32)) ? e[f] : 0.f;
        }
#pragma unroll
        for (int off = 1; off < 16; off <<= 1) {
            S32 += __shfl_xor(S32, off);
            S8  += __shfl_xor(S8, off);
        }
        float i32 = 0.5f / S32, i8 = 0.5f / S8;
#pragma unroll
        for (int f = 0; f < 4; ++f) {
            int j = f * 16 + ccol;
            float wgt = e[f] * i32 + (((j >= r + 25) && (j <= r + 32)) ? e[f] * i8 : 0.f);
            int byt = ((r * 64 + j) * 2) ^ ((r & 7) << 4);
            *reinterpret_cast<bf16*>(reinterpret_cast<char*>(wlds) + byt) = f2b(wgt);
        }
    }
    __syncthreads();

    short8 wa[2];
#pragma unroll
    for (int ks = 0; ks < 2; ++ks) {
        int byt = ((lrow * 64 + ks * 32 + koff) * 2) ^ ((lrow & 7) << 4);
        wa[ks] = *reinterpret_cast<const short8*>(reinterpret_cast<const char*>(wlds) + byt);
    }
    const bf16* vbase = vT + (size_t)b * Dd * KROWS + L0;
    bf16* obase = merged + ((size_t)(b * Ll + L0 + ccol)) * Dd;
    for (int c = 0; c < 6; ++c) {
#pragma unroll
        for (int fn = 0; fn < 8; ++fn) {
            int nr = c * 128 + fn * 16;
            floatx4 acc = {};
#pragma unroll
            for (int ks = 0; ks < 2; ++ks) {
                short8 bb = *reinterpret_cast<const short8*>(vbase + (size_t)(nr + lrow) * KROWS + ks * 32 + koff);
                acc = __builtin_amdgcn_mfma_f32_16x16x32_bf16(bb, wa[ks], acc, 0, 0, 0);
            }
            short4s pk;
#pragma unroll
            for (int rr = 0; rr < 4; ++rr) pk[rr] = f2bs(acc[rr]);
            *reinterpret_cast<short4s*>(obase + nr + crow) = pk;
        }
    }
}

extern "C" void kernel_launch(void* const* d_in, const int* in_sizes, int n_in,
                              void* d_out, int out_size, void* d_ws, size_t ws_size,
                              hipStream_t stream) {
    const float* hidden = (const float*)d_in[0];
    const float* sal    = (const float*)d_in[1];
    const float* gw1    = (const float*)d_in[2];
    const float* gb1    = (const float*)d_in[3];
    const float* gw2    = (const float*)d_in[4];
    const float* gb2    = (const float*)d_in[5];
    const float* wq     = (const float*)d_in[6];
    const float* bq     = (const float*)d_in[7];
    const float* wk     = (const float*)d_in[8];
    const float* bk     = (const float*)d_in[9];
    const float* wv     = (const float*)d_in[10];
    const float* bv     = (const float*)d_in[11];
    const float* wo     = (const float*)d_in[12];
    const float* bo     = (const float*)d_in[13];
    float* out = (float*)d_out;

    const size_t nBL  = (size_t)BL * Dd;
    const size_t nPad = (size_t)Bb * KROWS * Dd;
    char* p = (char*)d_ws;
    bf16* h_b = (bf16*)p; p += nBL * 2;
    bf16* q_b = (bf16*)p; p += nBL * 2;
    bf16* kpd = (bf16*)p; p += nPad * 2;
    bf16* vT  = (bf16*)p; p += nPad * 2;
    bf16* m_b = (bf16*)p; p += nBL * 2;
    bf16* w_b = (bf16*)p; p += (size_t)4 * Dd * Dd * 2;

    prep_gate_kernel<<<dim3(PREP_VB + GATE_VB), 256, 0, stream>>>(
        wq, wk, wv, wo, bk, bv, hidden, sal, gw1, gb1, gw2, gb2, w_b, kpd, vT, h_b);
    gemm_qkv<<<dim3(576), 256, 0, stream>>>(h_b, w_b, bq, bk, bv, q_b, kpd, vT);
    attn_kernel<<<dim3(256), 64, 0, stream>>>(q_b, kpd, vT, m_b);
    gemm_out<<<dim3(384), 256, 0, stream>>>(m_b, w_b + (size_t)3 * Dd * Dd, bo, h_b, out);
}

// Round 9
// 76.856 us; speedup vs baseline: 8.4159x; 1.0367x over previous
//
#include <hip/hip_runtime.h>
#include <hip/hip_bf16.h>
#include <stdint.h>

#define Bb 2
#define Ll 2048
#define Dd 768
#define HID 32
#define BL (Bb*Ll)          // 4096
#define KPAD 32
#define KROWS (KPAD+Ll+16)  // 2096

typedef __hip_bfloat16 bf16;
typedef __attribute__((ext_vector_type(8))) short short8;
typedef __attribute__((ext_vector_type(4))) short short4s;
typedef __attribute__((ext_vector_type(4))) float floatx4;

__device__ __forceinline__ float b2f(short u) {
    union { float f; unsigned i; } x; x.i = ((unsigned)(unsigned short)u) << 16; return x.f;
}
__device__ __forceinline__ bf16 f2b(float x) { return __float2bfloat16(x); }
__device__ __forceinline__ short f2bs(float x) {
    bf16 t = __float2bfloat16(x);
    union { bf16 h; short s; } u; u.h = t; return u.s;
}

typedef __attribute__((address_space(1))) const unsigned int guint;
typedef __attribute__((address_space(3))) unsigned int luint;
__device__ __forceinline__ void gload16(const bf16* g, bf16* l) {
    __builtin_amdgcn_global_load_lds((guint*)g, (luint*)l, 16, 0, 0);
}

// ============ prep (weights->bf16, K/V pads) + gate MLP, fused, independent blocks ============
#define CONV_VB 2304                 // 4*768*768/4 float4 / 256
#define KP_VB   (Bb*48)              // 96
#define VT_VB   ((Bb*Dd*48)/256)     // 288
#define PREP_VB (CONV_VB+KP_VB+VT_VB)   // 2688
#define GATE_VB (BL/8)               // 512
__global__ __launch_bounds__(256) void prep_gate_kernel(
        const float* __restrict__ wq, const float* __restrict__ wk,
        const float* __restrict__ wv, const float* __restrict__ wo,
        const float* __restrict__ bk, const float* __restrict__ bv,
        const float* __restrict__ hidden, const float* __restrict__ sal,
        const float* __restrict__ gw1, const float* __restrict__ gb1,
        const float* __restrict__ gw2, const float* __restrict__ gb2,
        bf16* __restrict__ wout, bf16* __restrict__ kp, bf16* __restrict__ vT,
        bf16* __restrict__ h_b) {
    __shared__ bf16 g2t[32 * 770];      // transposed gw2, row-padded to 770 (bank-clean)
    __shared__ float h1s[8][HID];
    int bx = blockIdx.x, tid = threadIdx.x;
    if (bx < CONV_VB) {
        int idx = bx * 256 + tid;
        const int per = Dd * Dd / 4;
        int w = idx / per, r = idx % per;
        const float* src = (w == 0) ? wq : (w == 1) ? wk : (w == 2) ? wv : wo;
        float4 v = reinterpret_cast<const float4*>(src)[r];
        bf16* o = wout + (size_t)w * Dd * Dd + (size_t)r * 4;
        o[0] = f2b(v.x); o[1] = f2b(v.y); o[2] = f2b(v.z); o[3] = f2b(v.w);
    } else if (bx < CONV_VB + KP_VB) {
        int pb = bx - CONV_VB;
        int b = pb / 48, c = pb % 48;
        int row = (c < 32) ? c : (KPAD + Ll + (c - 32));
        size_t base = ((size_t)b * KROWS + row) * Dd;
        for (int i = tid; i < Dd; i += 256)
            kp[base + i] = (c < 32) ? f2b(bk[i]) : f2b(0.f);
    } else if (bx < PREP_VB) {
        int o = (bx - CONV_VB - KP_VB) * 256 + tid;
        int b = o / (Dd * 48); int rem = o - b * Dd * 48;
        int n = rem / 48, c = rem % 48;
        int col = (c < 32) ? c : (KPAD + Ll + (c - 32));
        vT[((size_t)b * Dd + n) * KROWS + col] = (c < 32) ? f2b(bv[n]) : f2b(0.f);
    } else {
        // ---- gate: 8 rows per block; per-block gw2 transpose into LDS (bf16) ----
        int row0 = (bx - PREP_VB) * 8;
#pragma unroll
        for (int k2 = 0; k2 < 24; ++k2) {              // 768*32 fp32 via float4
            int o4 = tid + k2 * 256;
            float4 v = reinterpret_cast<const float4*>(gw2)[o4];
            int d = o4 >> 3, j = (o4 & 7) * 4;         // flat = d*32 + j
            g2t[(j + 0) * 770 + d] = f2b(v.x);
            g2t[(j + 1) * 770 + d] = f2b(v.y);
            g2t[(j + 2) * 770 + d] = f2b(v.z);
            g2t[(j + 3) * 770 + d] = f2b(v.w);
        }
        {
            int rr = tid >> 5, j = tid & 31;
            float s = sal[row0 + rr];
            float x = s * gw1[j] + gb1[j];
            h1s[rr][j] = x / (1.f + __expf(-x));       // silu
        }
        __syncthreads();
#pragma unroll
        for (int dl = 0; dl < 3; ++dl) {
            int d = tid + dl * 256;
            float base = gb2[d];
            float acc[8];
#pragma unroll
            for (int rr = 0; rr < 8; ++rr) acc[rr] = base;
#pragma unroll
            for (int j = 0; j < HID; ++j) {
                float wj = b2f(*(const short*)&g2t[j * 770 + d]);   // 2-way alias = free
#pragma unroll
                for (int rr = 0; rr < 8; ++rr) acc[rr] += h1s[rr][j] * wj;
            }
#pragma unroll
            for (int rr = 0; rr < 8; ++rr) {
                float g = 1.f / (1.f + __expf(-acc[rr]));
                g = fminf(fmaxf(g, 0.05f), 0.95f);
                size_t off = (size_t)(row0 + rr) * Dd + d;
                h_b[off] = f2b(hidden[off] * g);
            }
        }
    }
}

// ---------------- m97-structure MFMA GEMM core, BK-parametric ----------------
template<int NF, int BK>   // NF: wave n-frags (4 -> BN=128, 2 -> BN=64); BK: 64 or 128
__device__ __forceinline__ void gemm_core(const bf16* __restrict__ Ag, const bf16* __restrict__ Wg,
                                          int m0, int n0, bf16* As, bf16* Bs,
                                          floatx4 (&acc)[4][NF]) {
    const int tid  = threadIdx.x;
    const int wave = tid >> 6, lane = tid & 63;
    const int lrow = lane & 15, koff = (lane >> 4) * 8;
    const int wm = (wave >> 1) * 64, wn = (wave & 1) * (NF * 16);
    const int RS = BK * 2;                 // LDS row stride in bytes
    const char* Asb = (const char*)As;
    const char* Bsb = (const char*)Bs;

    for (int k0 = 0; k0 < Dd; k0 += BK) {
#pragma unroll
        for (int c = 0; c < BK / 16; ++c) {        // A: 128 x BK
            int p = tid * 16 + c * 4096;
            int r = p / RS;
            int o = (p % RS) ^ ((r & 7) << 4);
            gload16(Ag + (size_t)(m0 + r) * Dd + k0 + (o >> 1),
                    As + (wave * 1024 + c * 4096) / 2);
        }
#pragma unroll
        for (int c = 0; c < NF * BK / 64; ++c) {   // B: NF*32 x BK
            int p = tid * 16 + c * 4096;
            int r = p / RS;
            int o = (p % RS) ^ ((r & 7) << 4);
            gload16(Wg + (size_t)(n0 + r) * Dd + k0 + (o >> 1),
                    Bs + (wave * 1024 + c * 4096) / 2);
        }
        __syncthreads();
#pragma unroll
        for (int kk = 0; kk < BK; kk += 32) {
            short8 a[4], b[NF];
#pragma unroll
            for (int i = 0; i < 4; ++i) {
                int row = wm + i * 16 + lrow;
                int byt = row * RS + (((kk + koff) * 2) ^ ((row & 7) << 4));
                a[i] = *reinterpret_cast<const short8*>(Asb + byt);
            }
#pragma unroll
            for (int j = 0; j < NF; ++j) {
                int row = wn + j * 16 + lrow;
                int byt = row * RS + (((kk + koff) * 2) ^ ((row & 7) << 4));
                b[j] = *reinterpret_cast<const short8*>(Bsb + byt);
            }
#pragma unroll
            for (int i = 0; i < 4; ++i)
#pragma unroll
                for (int j = 0; j < NF; ++j)
                    acc[i][j] = __builtin_amdgcn_mfma_f32_16x16x32_bf16(a[i], b[j], acc[i][j], 0, 0, 0);
        }
        __syncthreads();
    }
}

// ---------------- fused QKV GEMM (BK=128), k/v into padded arrays ----------------
__global__ __launch_bounds__(256, 2) void gemm_qkv(
        const bf16* __restrict__ A, const bf16* __restrict__ W3,
        const float* __restrict__ bq, const float* __restrict__ bk, const float* __restrict__ bv,
        bf16* __restrict__ qo, bf16* __restrict__ kp, bf16* __restrict__ vT) {
    __shared__ bf16 As[128 * 128];
    __shared__ bf16 Bs[128 * 128];
    int bid = blockIdx.x;
    int xcd = bid & 7, idx = bid >> 3;
    int mtile = (xcd >> 1) * 8 + (idx & 7);
    int ntile = (xcd & 1) * 9 + (idx >> 3);
    int tgt = ntile / 6;
    int n0 = (ntile % 6) * 128;
    int m0 = mtile * 128;
    const bf16* W = W3 + (size_t)tgt * Dd * Dd;
    const float* bias = (tgt == 0) ? bq : (tgt == 1) ? bk : bv;

    floatx4 acc[4][4] = {};
    gemm_core<4, 128>(A, W, m0, n0, As, Bs, acc);

    int wave = threadIdx.x >> 6, lane = threadIdx.x & 63;
    int wm = (wave >> 1) * 64, wn = (wave & 1) * 64;
    int crow = (lane >> 4) * 4, ccol = lane & 15;
#pragma unroll
    for (int i = 0; i < 4; ++i)
#pragma unroll
        for (int j = 0; j < 4; ++j) {
            int n = n0 + wn + j * 16 + ccol;
            float bb = bias[n];
            int m = m0 + wm + i * 16 + crow;
            int b_ = m >> 11, l = m & 2047;
            if (tgt == 2) {
                short4s pk;
#pragma unroll
                for (int rr = 0; rr < 4; ++rr) pk[rr] = f2bs(acc[i][j][rr] + bb);
                *reinterpret_cast<short4s*>(vT + ((size_t)b_ * Dd + n) * KROWS + KPAD + l) = pk;
            } else {
#pragma unroll
                for (int rr = 0; rr < 4; ++rr) {
                    size_t orow = (tgt == 0) ? (size_t)(m + rr)
                                             : ((size_t)b_ * KROWS + KPAD + l + rr);
                    bf16* outp = (tgt == 0) ? qo : kp;
                    outp[orow * Dd + n] = f2b(acc[i][j][rr] + bb);
                }
            }
        }
}

// ---------------- output GEMM (BK=64): out = merged @ wo^T + bo + h ----------------
__global__ __launch_bounds__(256, 2) void gemm_out(
        const bf16* __restrict__ A, const bf16* __restrict__ W,
        const float* __restrict__ bias, const bf16* __restrict__ addend,
        float* __restrict__ out) {
    __shared__ bf16 As[128 * 64];
    __shared__ bf16 Bs[64 * 64];
    int bid = blockIdx.x;
    int xcd = bid & 7, idx = bid >> 3;
    int mtile = (xcd >> 1) * 8 + (idx & 7);
    int ntile = (xcd & 1) * 6 + (idx >> 3);
    int n0 = ntile * 64, m0 = mtile * 128;

    floatx4 acc[4][2] = {};
    gemm_core<2, 64>(A, W, m0, n0, As, Bs, acc);

    int wave = threadIdx.x >> 6, lane = threadIdx.x & 63;
    int wm = (wave >> 1) * 64, wn = (wave & 1) * 32;
    int crow = (lane >> 4) * 4, ccol = lane & 15;
#pragma unroll
    for (int i = 0; i < 4; ++i)
#pragma unroll
        for (int j = 0; j < 2; ++j) {
            int n = n0 + wn + j * 16 + ccol;
            float bb = bias[n];
#pragma unroll
            for (int rr = 0; rr < 4; ++rr) {
                int m = m0 + wm + i * 16 + crow + rr;
                size_t o = (size_t)m * Dd + n;
                out[o] = acc[i][j][rr] + bb + b2f(*(const short*)(addend + o));
            }
        }
}

// ---------------- MFMA banded sliding-window attention, 8 waves per group ----------------
// 256 blocks x 512 threads. Each block owns one 16-query-row group.
// QK^T: 24 k-slices split 8 ways -> per-wave partial S in LDS -> barrier -> each wave
// reduces + does banded softmax redundantly; PV: 768 output cols split 8 ways (96 each).
#define AW 8
__global__ __launch_bounds__(512) void attn_kernel(
        const bf16* __restrict__ q, const bf16* __restrict__ kp, const bf16* __restrict__ vT,
        bf16* __restrict__ merged) {
    __shared__ float Sp[AW][16][66];       // partial scores; stride 66 -> 2-way banks (free)
    __shared__ bf16 wlds[AW][16 * 64];     // per-wave W~ bounce, XOR-swizzled
    const int tid = threadIdx.x;
    const int wv = tid >> 6, lane = tid & 63;
    const int bid = blockIdx.x;                    // 256
    const int g = (bid & 7) * 32 + (bid >> 3);     // XCD-chunked, bijective
    const int b = g >> 7, L0 = (g & 127) * 16;
    const int lrow = lane & 15, koff = (lane >> 4) * 8;
    const int crow = (lane >> 4) * 4, ccol = lane & 15;
    const float scale = 0.03608439182435161f;      // 1/sqrt(768)

    // ---- QK^T partial: wave wv covers k-dims [wv*96, wv*96+96)
    const bf16* qbase = q  + ((size_t)(b * Ll + L0 + lrow)) * Dd + koff + wv * 96;
    const bf16* kbase = kp + ((size_t)b * KROWS + L0 + lrow) * Dd + koff + wv * 96;
    floatx4 s4[4] = {};
#pragma unroll
    for (int ks = 0; ks < 3; ++ks) {
        short8 a = *reinterpret_cast<const short8*>(qbase + ks * 32);
#pragma unroll
        for (int f = 0; f < 4; ++f) {
            short8 bb = *reinterpret_cast<const short8*>(kbase + (size_t)f * 16 * Dd + ks * 32);
            s4[f] = __builtin_amdgcn_mfma_f32_16x16x32_bf16(a, bb, s4[f], 0, 0, 0);
        }
    }
#pragma unroll
    for (int f = 0; f < 4; ++f)
#pragma unroll
        for (int rr = 0; rr < 4; ++rr)
            Sp[wv][crow + rr][f * 16 + ccol] = s4[f][rr];
    __syncthreads();

    // ---- banded softmax (redundant per wave), rows r = crow+rr; lane col j = f*16+ccol
#pragma unroll
    for (int rr = 0; rr < 4; ++rr) {
        int r = crow + rr;
        float z[4], e[4];
#pragma unroll
        for (int f = 0; f < 4; ++f) {
            int j = f * 16 + ccol;
            float v = 0.f;
#pragma unroll
            for (int w = 0; w < AW; ++w) v += Sp[w][r][j];
            bool valid = (j >= r + 1) && (j <= r + 32);
            z[f] = valid ? v * scale : -3.0e38f;
        }
        float m = fmaxf(fmaxf(z[0], z[1]), fmaxf(z[2], z[3]));
#pragma unroll
        for (int off = 1; off < 16; off <<= 1) m = fmaxf(m, __shfl_xor(m, off));
        float S32 = 0.f, S8 = 0.f;
#pragma unroll
        for (int f = 0; f < 4; ++f) {
            e[f] = __expf(z[f] - m);
            S32 += e[f];
            int j = f * 16 + ccol;
            S8 += ((j >= r + 25) && (j <= r + 32)) ? e[f] : 0.f;
        }
#pragma unroll
        for (int off = 1; off < 16; off <<= 1) {
            S32 += __shfl_xor(S32, off);
            S8  += __shfl_xor(S8, off);
        }
        float i32 = 0.5f / S32, i8 = 0.5f / S8;
#pragma unroll
        for (int f = 0; f < 4; ++f) {
            int j = f * 16 + ccol;
            float wgt = e[f] * i32 + (((j >= r + 25) && (j <= r + 32)) ? e[f] * i8 : 0.f);
            int byt = ((r * 64 + j) * 2) ^ ((r & 7) << 4);
            *reinterpret_cast<bf16*>(reinterpret_cast<char*>(wlds[wv]) + byt) = f2b(wgt);
        }
    }
    // same-wave LDS write->read: ordered by lgkmcnt, no barrier needed

    // ---- PV: wave wv covers output cols [wv*96, wv*96+96)
    short8 wa[2];
#pragma unroll
    for (int ks = 0; ks < 2; ++ks) {
        int byt = ((lrow * 64 + ks * 32 + koff) * 2) ^ ((lrow & 7) << 4);
        wa[ks] = *reinterpret_cast<const short8*>(reinterpret_cast<const char*>(wlds[wv]) + byt);
    }
    const bf16* vbase = vT + (size_t)b * Dd * KROWS + L0;
    bf16* obase = merged + ((size_t)(b * Ll + L0 + ccol)) * Dd;
#pragma unroll
    for (int fn = 0; fn < 6; ++fn) {
        int nr = wv * 96 + fn * 16;
        floatx4 acc = {};
#pragma unroll
        for (int ks = 0; ks < 2; ++ks) {
            short8 bb = *reinterpret_cast<const short8*>(vbase + (size_t)(nr + lrow) * KROWS + ks * 32 + koff);
            acc = __builtin_amdgcn_mfma_f32_16x16x32_bf16(bb, wa[ks], acc, 0, 0, 0);
        }
        short4s pk;
#pragma unroll
        for (int rr = 0; rr < 4; ++rr) pk[rr] = f2bs(acc[rr]);
        *reinterpret_cast<short4s*>(obase + nr + crow) = pk;
    }
}

extern "C" void kernel_launch(void* const* d_in, const int* in_sizes, int n_in,
                              void* d_out, int out_size, void* d_ws, size_t ws_size,
                              hipStream_t stream) {
    const float* hidden = (const float*)d_in[0];
    const float* sal    = (const float*)d_in[1];
    const float* gw1    = (const float*)d_in[2];
    const float* gb1    = (const float*)d_in[3];
    const float* gw2    = (const float*)d_in[4];
    const float* gb2    = (const float*)d_in[5];
    const float* wq     = (const float*)d_in[6];
    const float* bq     = (const float*)d_in[7];
    const float* wk     = (const float*)d_in[8];
    const float* bk     = (const float*)d_in[9];
    const float* wv     = (const float*)d_in[10];
    const float* bv     = (const float*)d_in[11];
    const float* wo     = (const float*)d_in[12];
    const float* bo     = (const float*)d_in[13];
    float* out = (float*)d_out;

    const size_t nBL  = (size_t)BL * Dd;
    const size_t nPad = (size_t)Bb * KROWS * Dd;
    char* p = (char*)d_ws;
    bf16* h_b = (bf16*)p; p += nBL * 2;
    bf16* q_b = (bf16*)p; p += nBL * 2;
    bf16* kpd = (bf16*)p; p += nPad * 2;
    bf16* vT  = (bf16*)p; p += nPad * 2;
    bf16* m_b = (bf16*)p; p += nBL * 2;
    bf16* w_b = (bf16*)p; p += (size_t)4 * Dd * Dd * 2;

    prep_gate_kernel<<<dim3(PREP_VB + GATE_VB), 256, 0, stream>>>(
        wq, wk, wv, wo, bk, bv, hidden, sal, gw1, gb1, gw2, gb2, w_b, kpd, vT, h_b);
    gemm_qkv<<<dim3(576), 256, 0, stream>>>(h_b, w_b, bq, bk, bv, q_b, kpd, vT);
    attn_kernel<<<dim3(256), 512, 0, stream>>>(q_b, kpd, vT, m_b);
    gemm_out<<<dim3(384), 256, 0, stream>>>(m_b, w_b + (size_t)3 * Dd * Dd, bo, h_b, out);
}